// Round 7
// baseline (203.501 us; speedup 1.0000x reference)
//
#include <hip/hip_runtime.h>
#include <math.h>

#define BB 16
#define SS 256
#define FF 512
#define EE 128
#define HH 64
#define GG 192  // 3H
#define LL 8

__device__ __forceinline__ float sigmoid_f(float x) {
    return 1.0f / (1.0f + __expf(-x));
}
__device__ __forceinline__ float tanh_f(float x) {
    // 1 - 2/(1+e^{2x}): saturates cleanly to ±1, no NaN for large |x|
    return 1.0f - 2.0f / (1.0f + __expf(2.0f * x));
}

// ---------------------------------------------------------------------------
// Generic C[m,n] = sum_k A[m,k] * Bm[n,k] + bias[n]
// Tile: 32 rows x 64 cols, K chunks of 64. Block = 256 threads.
// Requires M % 32 == 0, K % 64 == 0. N handled with guards.
// ---------------------------------------------------------------------------
__device__ __forceinline__ void gemm_bt_body(
    const float* __restrict__ A, const float* __restrict__ Bm,
    const float* __restrict__ bias, float* __restrict__ C,
    int N, int K)
{
    __shared__ float As[32][68];
    __shared__ float Bs[64][68];
    const int t = threadIdx.x;
    const int row0 = blockIdx.x * 32;
    const int col0 = blockIdx.y * 64;
    const int tr = t & 7;        // 0..7 row-group
    const int tc = t >> 3;       // 0..31 col-group
    float acc[4][2] = {{0.f,0.f},{0.f,0.f},{0.f,0.f},{0.f,0.f}};

    for (int k0 = 0; k0 < K; k0 += 64) {
        {
            int r = t >> 3;          // 0..31
            int q = t & 7;           // 0..7
            const float* src = &A[(size_t)(row0 + r) * K + k0];
            #pragma unroll
            for (int it = 0; it < 2; ++it) {
                int kk = (q + it * 8) * 4;
                *(float4*)&As[r][kk] = *(const float4*)&src[kk];
            }
        }
        {
            int r = t >> 2;          // 0..63
            int q = t & 3;           // 0..3
            int n = col0 + r;
            #pragma unroll
            for (int it = 0; it < 4; ++it) {
                int kk = (q + it * 4) * 4;
                float4 v = {0.f, 0.f, 0.f, 0.f};
                if (n < N) v = *(const float4*)&Bm[(size_t)n * K + k0 + kk];
                *(float4*)&Bs[r][kk] = v;
            }
        }
        __syncthreads();
        #pragma unroll
        for (int k = 0; k < 64; k += 4) {
            float4 av[4], bv[2];
            #pragma unroll
            for (int i = 0; i < 4; ++i) av[i] = *(const float4*)&As[tr + 8*i][k];
            #pragma unroll
            for (int j = 0; j < 2; ++j) bv[j] = *(const float4*)&Bs[tc + 32*j][k];
            #pragma unroll
            for (int i = 0; i < 4; ++i)
                #pragma unroll
                for (int j = 0; j < 2; ++j)
                    acc[i][j] += av[i].x*bv[j].x + av[i].y*bv[j].y
                               + av[i].z*bv[j].z + av[i].w*bv[j].w;
        }
        __syncthreads();
    }

    #pragma unroll
    for (int i = 0; i < 4; ++i) {
        int r = row0 + tr + 8*i;
        #pragma unroll
        for (int j = 0; j < 2; ++j) {
            int c = col0 + tc + 32*j;
            if (c < N) C[(size_t)r * N + c] = acc[i][j] + bias[c];
        }
    }
}

__global__ __launch_bounds__(256) void gemm_bt(
    const float* __restrict__ A, const float* __restrict__ Bm,
    const float* __restrict__ bias, float* __restrict__ C,
    int N, int K)
{
    gemm_bt_body(A, Bm, bias, C, N, K);
}

// Two GEMMs sharing A, selected by blockIdx.z (saves a launch).
__global__ __launch_bounds__(256) void gemm_bt_dual(
    const float* __restrict__ A,
    const float* __restrict__ B0, const float* __restrict__ bias0, float* __restrict__ C0,
    const float* __restrict__ B1, const float* __restrict__ bias1, float* __restrict__ C1,
    int N, int K)
{
    const float* Bm   = blockIdx.z ? B1    : B0;
    const float* bias = blockIdx.z ? bias1 : bias0;
    float*       C    = blockIdx.z ? C1    : C0;
    gemm_bt_body(A, Bm, bias, C, N, K);
}

// ---------------------------------------------------------------------------
// GRU scan. One chain per block, three waves per block (one gate per wave):
// grid 32 x 192. Lane (g,j) holds row g*64+j of Whh (asm-pinned loads).
// KEY FIX (r7): __syncthreads() drains vmcnt(0) every step, serializing the
// next-step xp prefetch loads AND the hrow store back into the recurrence
// critical path (~400+ cyc/step of the measured 1088). The LDS gh exchange
// only needs lgkmcnt visibility, so use `ds_write; s_waitcnt lgkmcnt(0);
// s_barrier` and let global ops stay in flight across the barrier (T4
// principle: never drain vmcnt to 0 in the loop). Double-buffered gh_s makes
// one barrier per step race-free.
// ---------------------------------------------------------------------------
__global__ __launch_bounds__(192, 1)
__attribute__((amdgpu_waves_per_eu(1, 1)))
void gru_kernel(
    const float* __restrict__ xpa, const float* __restrict__ xpb,
    const float* __restrict__ Whh_a, const float* __restrict__ bhh_a,
    const float* __restrict__ Whh_b, const float* __restrict__ bhh_b,
    float* __restrict__ hs_a, float* __restrict__ hs_b)
{
    const int blk = blockIdx.x;      // 0..31
    const int b = blk >> 1;
    const int which = blk & 1;
    const float* xp  = which ? xpb   : xpa;
    const float* Whh = which ? Whh_b : Whh_a;
    const float* bhh = which ? bhh_b : bhh_a;
    float* hs        = which ? hs_b  : hs_a;

    const int t = threadIdx.x;       // 0..191
    const int g = t >> 6;            // gate: 0=r, 1=z, 2=n
    const int j = t & 63;            // lane

    __shared__ float gh_s[2][GG];

    // 64 weights of row g*64+j, pinned via empty asm (blocks remat).
    float4 w[16];
    {
        const float4* wrow = (const float4*)&Whh[(size_t)(g * 64 + j) * HH];
        #pragma unroll
        for (int k = 0; k < 16; ++k) {
            w[k] = wrow[k];
            asm volatile("" : "+v"(w[k].x), "+v"(w[k].y), "+v"(w[k].z), "+v"(w[k].w));
        }
    }
    const float bh = bhh[g * 64 + j];

    const float* xrow = xp + (size_t)b * SS * GG;
    float* hrow = hs + (size_t)b * SS * HH;
    float hcur = 0.f;

    // prefetch step 0: own-gate x, plus xn (needed by the h-update)
    float xg = xrow[g * 64 + j];
    float xn = xrow[128 + j];

#define RL(v, k) __int_as_float(__builtin_amdgcn_readlane(__float_as_int(v), (k)))

    for (int s = 0; s < SS; ++s) {
        // Prefetch next step's xp (last iter reads past this xp array into
        // the adjacent workspace region — harmless, value discarded). These
        // loads now stay in flight across the barrier below.
        const float* nx = xrow + GG;
        float nxg = nx[g * 64 + j];
        float nxn = nx[128 + j];

        // own-gate dot:  pre = bh + Whh[row] . h   (4 independent chains)
        float a0 = bh, a1 = 0.f, a2 = 0.f, a3 = 0.f;
        #pragma unroll
        for (int k = 0; k < 16; ++k) {
            float4 wk = w[k];
            float h0 = RL(hcur, 4*k + 0);
            float h1 = RL(hcur, 4*k + 1);
            float h2 = RL(hcur, 4*k + 2);
            float h3 = RL(hcur, 4*k + 3);
            a0 = fmaf(wk.x, h0, a0);
            a1 = fmaf(wk.y, h1, a1);
            a2 = fmaf(wk.z, h2, a2);
            a3 = fmaf(wk.w, h3, a3);
        }
        float pre = (a0 + a1) + (a2 + a3);
        // fold x into r,z pre-activations; n keeps x outside the r* term
        gh_s[s & 1][t] = (g < 2) ? (xg + pre) : pre;

        // LDS-only barrier: wait ds_write visibility, do NOT drain vmcnt.
        asm volatile("s_waitcnt lgkmcnt(0)" ::: "memory");
        __builtin_amdgcn_s_barrier();
        asm volatile("" ::: "memory");

        float ghr = gh_s[s & 1][j];
        float ghz = gh_s[s & 1][64 + j];
        float ghn = gh_s[s & 1][128 + j];
        float r = sigmoid_f(ghr);
        float z = sigmoid_f(ghz);
        float n = tanh_f(xn + r * ghn);
        hcur = fmaf(z, hcur - n, n);   // (1-z)*n + z*h
        if (g == 0) hrow[j] = hcur;

        xg = nxg; xn = nxn;
        xrow += GG;
        hrow += HH;
    }
#undef RL
}

// ---------------------------------------------------------------------------
// Per (b,j): wj = exp(h_alpha . Wa + ba) * M;  val[e] = tanh(h_beta . Wb[e] + bb[e]) * emb[e] * wj
// Grid: B*S blocks x 128 threads (thread = e).
// ---------------------------------------------------------------------------
__global__ __launch_bounds__(128) void attn_val_kernel(
    const float* __restrict__ h_alpha, const float* __restrict__ h_beta,
    const float* __restrict__ emb, const float* __restrict__ M,
    const float* __restrict__ Wa, const float* __restrict__ ba,
    const float* __restrict__ Wb, const float* __restrict__ bb,
    float* __restrict__ val, float* __restrict__ wj)
{
    const int bj = blockIdx.x;       // 0..B*S-1
    const int t = threadIdx.x;       // 0..127
    __shared__ float hb_s[HH];
    __shared__ float wj_s;

    if (t < 64) {
        hb_s[t] = h_beta[(size_t)bj * HH + t];
        float p = h_alpha[(size_t)bj * HH + t] * Wa[t];
        #pragma unroll
        for (int off = 32; off > 0; off >>= 1) p += __shfl_down(p, off);
        if (t == 0) {
            float a = __expf(p + ba[0]) * M[bj];
            wj_s = a;
            wj[bj] = a;
        }
    }
    __syncthreads();

    float acc = bb[t];
    const float4* wrow = (const float4*)&Wb[(size_t)t * HH];
    #pragma unroll
    for (int k = 0; k < 16; ++k) {
        float4 w4 = wrow[k];
        float4 h4 = *(const float4*)&hb_s[k * 4];
        acc += w4.x*h4.x + w4.y*h4.y + w4.z*h4.z + w4.w*h4.w;
    }
    float bw = tanh_f(acc);
    val[(size_t)bj * EE + t] = bw * emb[(size_t)bj * EE + t] * wj_s;
}

// ---------------------------------------------------------------------------
// Suffix scan over j: weighted[b,i,e] = (sum_{j>=i} val[b,j,e]) / (sum_{j>=i} wj[b,j] + 1e-10)
// Grid: B blocks x 128 threads (thread = e).
// ---------------------------------------------------------------------------
__global__ __launch_bounds__(128) void scan_kernel(
    const float* __restrict__ val, const float* __restrict__ wj,
    float* __restrict__ wtd)
{
    const int b = blockIdx.x;
    const int t = threadIdx.x;   // e
    float se = 0.f;
    float d = 1e-10f;
    for (int j = SS - 1; j >= 0; --j) {
        size_t idx = ((size_t)(b * SS + j)) * EE + t;
        se += val[idx];
        d += wj[b * SS + j];
        wtd[idx] = se / d;
    }
}

// ---------------------------------------------------------------------------
// all_output[b,s,l] = (weighted[b,s,:] . Wp[l,:] + bp[l]) * M[b,s]
// Block: 32 rows x 8 l = 256 threads. Grid: 4096/32 = 128 blocks.
// ---------------------------------------------------------------------------
__global__ __launch_bounds__(256) void proj_kernel(
    const float* __restrict__ wtd, const float* __restrict__ Wp,
    const float* __restrict__ bp, const float* __restrict__ M,
    float* __restrict__ out)
{
    __shared__ float wt_s[32][132];
    __shared__ float wp_s[8][132];
    const int t = threadIdx.x;
    const int row0 = blockIdx.x * 32;

    {   // stage weighted tile: 32 x 128
        int r = t >> 3;          // 0..31
        int q = t & 7;           // 0..7
        const float* src = &wtd[(size_t)(row0 + r) * EE];
        #pragma unroll
        for (int it = 0; it < 4; ++it) {
            int kk = (q + it * 8) * 4;
            *(float4*)&wt_s[r][kk] = *(const float4*)&src[kk];
        }
    }
    {   // stage Wp: 8 x 128
        int r = t >> 5;          // 0..7
        int q = t & 31;          // 0..31
        *(float4*)&wp_s[r][q * 4] = *(const float4*)&Wp[(size_t)r * EE + q * 4];
    }
    __syncthreads();

    const int r = t >> 3, l = t & 7;
    float acc = 0.f;
    #pragma unroll
    for (int i = 0; i < 32; ++i) {
        float4 a = *(const float4*)&wt_s[r][i * 4];
        float4 w = *(const float4*)&wp_s[l][i * 4];
        acc += a.x*w.x + a.y*w.y + a.z*w.z + a.w*w.w;
    }
    const int row = row0 + r;
    out[(size_t)row * LL + l] = (acc + bp[l]) * M[row];
}

// ---------------------------------------------------------------------------
// cur_output[b,l] = sum_s all_output[b,s,l] * cur_M[b,s]
// Grid: B blocks x 256 threads.
// ---------------------------------------------------------------------------
__global__ __launch_bounds__(256) void cur_kernel(
    const float* __restrict__ out_all, const float* __restrict__ curM,
    float* __restrict__ out_cur)
{
    const int b = blockIdx.x;
    const int t = threadIdx.x;
    const int l = t & 7, c = t >> 3;   // c: 0..31
    float p = 0.f;
    #pragma unroll
    for (int k = 0; k < 8; ++k) {
        int s = c + k * 32;
        p += out_all[((size_t)(b * SS + s)) * LL + l] * curM[b * SS + s];
    }
    __shared__ float red[32][9];
    red[c][l] = p;
    __syncthreads();
    if (t < 8) {
        float sum = 0.f;
        for (int c2 = 0; c2 < 32; ++c2) sum += red[c2][t];
        out_cur[b * LL + t] = sum;
    }
}

// ---------------------------------------------------------------------------
extern "C" void kernel_launch(void* const* d_in, const int* in_sizes, int n_in,
                              void* d_out, int out_size, void* d_ws, size_t ws_size,
                              hipStream_t stream)
{
    const float* X       = (const float*)d_in[0];
    const float* M       = (const float*)d_in[1];
    const float* cur_M   = (const float*)d_in[2];
    const float* W_embed = (const float*)d_in[3];
    const float* b_embed = (const float*)d_in[4];
    const float* Wih_a   = (const float*)d_in[5];
    const float* Whh_a   = (const float*)d_in[6];
    const float* bih_a   = (const float*)d_in[7];
    const float* bhh_a   = (const float*)d_in[8];
    const float* Wih_b   = (const float*)d_in[9];
    const float* Whh_b   = (const float*)d_in[10];
    const float* bih_b   = (const float*)d_in[11];
    const float* bhh_b   = (const float*)d_in[12];
    const float* Wb      = (const float*)d_in[13];
    const float* bb      = (const float*)d_in[14];
    const float* Wa      = (const float*)d_in[15];
    const float* ba      = (const float*)d_in[16];
    const float* Wp      = (const float*)d_in[17];
    const float* bp      = (const float*)d_in[18];
    float* out = (float*)d_out;

    float* ws  = (float*)d_ws;
    float* emb = ws;                          // B*S*E   = 524288
    float* xpa = emb + (size_t)BB*SS*EE;      // B*S*192 = 786432
    float* xpb = xpa + (size_t)BB*SS*GG;
    float* ha  = xpb + (size_t)BB*SS*GG;      // B*S*H
    float* hb  = ha  + (size_t)BB*SS*HH;
    float* val = hb  + (size_t)BB*SS*HH;      // B*S*E
    float* wjv = val + (size_t)BB*SS*EE;      // B*S
    float* wtd = wjv + (size_t)BB*SS;         // B*S*E

    const int ROWS = BB * SS;                 // 4096

    // 1) emb = X @ W_embed^T + b_embed
    gemm_bt<<<dim3(ROWS/32, EE/64), 256, 0, stream>>>(X, W_embed, b_embed, emb, EE, FF);
    // 2) xp_a / xp_b = emb @ Wih^T + bih  (one dual launch, z selects GRU)
    gemm_bt_dual<<<dim3(ROWS/32, (GG+63)/64, 2), 256, 0, stream>>>(
        emb, Wih_a, bih_a, xpa, Wih_b, bih_b, xpb, GG, EE);
    // 3) both GRU scans (32 chains, 3 waves each — one gate per wave)
    gru_kernel<<<32, 192, 0, stream>>>(xpa, xpb, Whh_a, bhh_a, Whh_b, bhh_b, ha, hb);
    // 4) attention weights + per-j values
    attn_val_kernel<<<ROWS, 128, 0, stream>>>(ha, hb, emb, M, Wa, ba, Wb, bb, val, wjv);
    // 5) suffix scan -> weighted
    scan_kernel<<<BB, 128, 0, stream>>>(val, wjv, wtd);
    // 6) projection -> all_output
    proj_kernel<<<ROWS/32, 256, 0, stream>>>(wtd, Wp, bp, M, out);
    // 7) cur_output
    cur_kernel<<<BB, 256, 0, stream>>>(out, cur_M, out + (size_t)BB*SS*LL);
}